// Round 1
// baseline (374.876 us; speedup 1.0000x reference)
//
#include <hip/hip_runtime.h>

#define B_SZ 4
#define SEQ 4096
#define DIN 1024
#define DH 1024
#define DOUT 1024
#define NBLK 8
#define MTOK (B_SZ * SEQ)      // 16384 tokens
#define CHUNK 64
#define NCHUNK (SEQ / CHUNK)   // 64

typedef _Float16 half8 __attribute__((ext_vector_type(8)));
typedef _Float16 half4v __attribute__((ext_vector_type(4)));
typedef float f32x4 __attribute__((ext_vector_type(4)));

// async global->LDS, 16B per lane. LDS dest must be wave-uniform; HW scatters
// to base + lane*16 (so LDS tiles are UNPADDED and laid out in lane order).
__device__ __forceinline__ void gl_lds16(const void* g, void* l) {
  __builtin_amdgcn_global_load_lds((__attribute__((address_space(1))) void*)g,
                                   (__attribute__((address_space(3))) void*)l,
                                   16, 0, 0);
}

// Swizzled xp-tile index (returns HALF index). byte = r*256 + c*2, XOR'd with
// (r&7)<<4: spreads the 256B-stride rows over 8 distinct 16B bank slots so the
// half8 A-frag reads (16 consecutive rows, same 16B col) are 2-way (free, G4).
// 16B alignment is preserved (XOR touches byte bits 4..6 only).
__device__ __forceinline__ int swz_h(int r, int c) {
  return (((r << 8) | (c << 1)) ^ ((r & 7) << 4)) >> 1;
}

// ---------------------------------------------------------------- prep
// One dispatch: blocks [0,16384) convert x fp32->fp16 (float4/thread);
// blocks [16384, 16384+576) do the 4 weight transposes (fp32->fp16, [R][C]->[C][R]).
__global__ __launch_bounds__(256)
void prep_kernel(const float* __restrict__ x, _Float16* __restrict__ x_h,
                 const float* __restrict__ Win, const float* __restrict__ Wout,
                 const float* __restrict__ Wgx, const float* __restrict__ Wga,
                 _Float16* __restrict__ WinT, _Float16* __restrict__ WoutT,
                 _Float16* __restrict__ WgxT, _Float16* __restrict__ WgaT) {
  __shared__ float tile[64][65];
  if (blockIdx.x < 16384) {
    const int gid = blockIdx.x * 256 + threadIdx.x;
    const float4 v = ((const float4*)x)[gid];
    half4v h;
    h[0] = (_Float16)v.x; h[1] = (_Float16)v.y; h[2] = (_Float16)v.z; h[3] = (_Float16)v.w;
    ((half4v*)x_h)[gid] = h;
    return;
  }
  int t = blockIdx.x - 16384;
  const float* src; _Float16* dst; int C; size_t bo = 0;
  if (t < 256)      { src = Win;  dst = WinT;  C = 1024; }
  else if (t < 512) { src = Wout; dst = WoutT; C = 1024; t -= 256; }
  else if (t < 544) { int u = t - 512; src = Wgx; dst = WgxT; C = 128;
                      bo = (size_t)(u >> 2) * (128 * 128); t = u & 3; }
  else              { int u = t - 544; src = Wga; dst = WgaT; C = 128;
                      bo = (size_t)(u >> 2) * (128 * 128); t = u & 3; }
  const int nbx = C >> 6;
  const int r0 = (t / nbx) * 64, c0 = (t % nbx) * 64;
  const int tr = threadIdx.x >> 6, tc = threadIdx.x & 63;
#pragma unroll
  for (int i = 0; i < 64; i += 4)
    tile[tr + i][tc] = src[bo + (size_t)(r0 + tr + i) * C + c0 + tc];
  __syncthreads();
#pragma unroll
  for (int i = 0; i < 64; i += 4) {
    const int cc = i + tr;
    dst[bo + (size_t)(c0 + cc) * C + r0 + tc] = (_Float16)tile[tc][cc];
  }
}

// ---------------------------------------------------------------- GEMM (m97 recipe)
// C[M,N] = A[M,K] * Bt[N,K]^T + bias ; 128x128 tile, 4 waves, BK=64, f16 MFMA.
// Epilogue stores j-INNERMOST: 4 stores cover contiguous 64 elems -> full-line
// sector merge survives the concurrent main-loop L2 churn.
template <int OUT_F32>
__global__ __launch_bounds__(256)
void gemm_bt(const _Float16* __restrict__ A, const _Float16* __restrict__ Bt,
             const float* __restrict__ bias, void* __restrict__ C,
             int M, int N, int K) {
  __shared__ __align__(16) _Float16 As[128 * 64];
  __shared__ __align__(16) _Float16 Bs[128 * 64];
  const int tid = threadIdx.x;
  const int wave = tid >> 6, lane = tid & 63;
  const int m0 = blockIdx.x * 128, n0 = blockIdx.y * 128;
  const int wm = (wave >> 1) * 64, wn = (wave & 1) * 64;
  const int row = lane & 15, quad = lane >> 4;
  const int srow = lane >> 3, scol = (lane & 7) * 8;

  f32x4 acc[4][4] = {};
  for (int kt = 0; kt < K; kt += 64) {
#pragma unroll
    for (int ci = 0; ci < 4; ci++) {
      const int c = wave * 4 + ci;
      gl_lds16(A  + (size_t)(m0 + c * 8 + srow) * K + kt + scol, As + c * 512);
      gl_lds16(Bt + (size_t)(n0 + c * 8 + srow) * K + kt + scol, Bs + c * 512);
    }
    __syncthreads();
#pragma unroll
    for (int kk = 0; kk < 64; kk += 32) {
      half8 af[4], bf[4];
#pragma unroll
      for (int i = 0; i < 4; i++)
        af[i] = *(const half8*)&As[(wm + i * 16 + row) * 64 + kk + quad * 8];
#pragma unroll
      for (int i = 0; i < 4; i++)
        bf[i] = *(const half8*)&Bs[(wn + i * 16 + row) * 64 + kk + quad * 8];
#pragma unroll
      for (int i = 0; i < 4; i++)
#pragma unroll
        for (int j = 0; j < 4; j++)
          acc[i][j] = __builtin_amdgcn_mfma_f32_16x16x32_f16(af[i], bf[j], acc[i][j], 0, 0, 0);
    }
    __syncthreads();
  }
  float bv[4];
#pragma unroll
  for (int j = 0; j < 4; j++) bv[j] = bias[n0 + wn + j * 16 + row];
#pragma unroll
  for (int i = 0; i < 4; i++) {
#pragma unroll
    for (int r = 0; r < 4; r++) {
      const int m = m0 + wm + i * 16 + quad * 4 + r;
      const size_t base = (size_t)m * N + n0 + wn + row;
#pragma unroll
      for (int j = 0; j < 4; j++) {
        const float v = acc[i][j][r] + bv[j];
        if (OUT_F32) ((float*)C)[base + j * 16] = v;
        else         ((_Float16*)C)[base + j * 16] = (_Float16)v;
      }
    }
  }
}

// ---------------------------------------------------------------- gemm1 + gates (fused)
// Key fact: gates block (m0, nb) consumes EXACTLY gemm1 block (m0, n0=nb*128)'s
// output tile xp[m0:m0+128, nb*128:(nb+1)*128]. Fusing removes the 32MB xp
// write + ~19MB re-read and the entire latency-bound (10% occupancy) gates
// dispatch. After the m97 main loop, the fp16 xp tile is written into the dead
// As/Bs LDS (XOR-swizzled), then the two 128x128x128 gate GEMMs read A-frags
// from LDS and weights direct from global (L2-resident: 128 blocks share nb).
// xv is re-read from the fp16 LDS tile -> bit-identical to the old fp16 xp
// path AND lets acc[4][4] die at the tile write (register pressure).
// Gate accumulators are SPLIT into two j-pair passes (64 VGPRs at a time) so
// peak VGPR stays at the main loop's level. jp loop is NOT unrolled and the
// chunk carries are stored per-pass so no register array is runtime-indexed.
__global__ __launch_bounds__(256)
void gemm1_gates(const _Float16* __restrict__ A, const _Float16* __restrict__ Bt,
                 const float* __restrict__ bias,
                 const _Float16* __restrict__ WxT, const _Float16* __restrict__ WaT,
                 const float* __restrict__ bgx, const float* __restrict__ bga,
                 const float* __restrict__ arp,
                 _Float16* __restrict__ a_out, _Float16* __restrict__ gx_out,
                 float* __restrict__ cA, float* __restrict__ cH) {
  __shared__ __align__(16) _Float16 smem[128 * 128];   // 32KB: As|Bs, then xp tile
  _Float16* const As = smem;
  _Float16* const Bs = smem + 128 * 64;
  const int tid = threadIdx.x;
  const int wave = tid >> 6, lane = tid & 63;
  const int m0 = blockIdx.x * 128, nb = blockIdx.y, n0 = nb * 128;
  const int wm = (wave >> 1) * 64, wn = (wave & 1) * 64;
  const int row = lane & 15, quad = lane >> 4;
  const int srow = lane >> 3, scol = (lane & 7) * 8;

  // ---- xp = x_h @ WinT^T + b_in (m97 main loop, K = DIN)
  f32x4 acc[4][4] = {};
  for (int kt = 0; kt < DIN; kt += 64) {
#pragma unroll
    for (int ci = 0; ci < 4; ci++) {
      const int c = wave * 4 + ci;
      gl_lds16(A  + (size_t)(m0 + c * 8 + srow) * DIN + kt + scol, As + c * 512);
      gl_lds16(Bt + (size_t)(n0 + c * 8 + srow) * DIN + kt + scol, Bs + c * 512);
    }
    __syncthreads();
#pragma unroll
    for (int kk = 0; kk < 64; kk += 32) {
      half8 af[4], bf[4];
#pragma unroll
      for (int i = 0; i < 4; i++)
        af[i] = *(const half8*)&As[(wm + i * 16 + row) * 64 + kk + quad * 8];
#pragma unroll
      for (int i = 0; i < 4; i++)
        bf[i] = *(const half8*)&Bs[(wn + i * 16 + row) * 64 + kk + quad * 8];
#pragma unroll
      for (int i = 0; i < 4; i++)
#pragma unroll
        for (int j = 0; j < 4; j++)
          acc[i][j] = __builtin_amdgcn_mfma_f32_16x16x32_f16(af[i], bf[j], acc[i][j], 0, 0, 0);
    }
    __syncthreads();   // last iter: all waves done reading As/Bs -> safe to overwrite
  }

  // ---- xp tile -> swizzled LDS (fp16). acc is DEAD after this block.
  {
    float bv[4];
#pragma unroll
    for (int j = 0; j < 4; j++) bv[j] = bias[n0 + wn + j * 16 + row];
#pragma unroll
    for (int i = 0; i < 4; i++)
#pragma unroll
      for (int r = 0; r < 4; r++) {
        const int tl = wm + i * 16 + quad * 4 + r;
#pragma unroll
        for (int j = 0; j < 4; j++)
          smem[swz_h(tl, wn + j * 16 + row)] = (_Float16)(acc[i][j][r] + bv[j]);
      }
  }
  __syncthreads();

  // ---- gate GEMMs + gate math + per-chunk (A,H) reduction (scan p1)
  const _Float16* const WxB = WxT + (size_t)nb * (128 * 128);
  const _Float16* const WaB = WaT + (size_t)nb * (128 * 128);
  const int b_idx = (m0 + wm) >> 12;
  const int c_idx = ((m0 + wm) & (SEQ - 1)) >> 6;
  const int cbase = c_idx * (B_SZ * DH) + b_idx * DH + n0 + wn + row;

#pragma unroll 1   // do NOT unroll: keeps one pass's 64 acc VGPRs live at a time
  for (int jp = 0; jp < 2; jp++) {
    f32x4 accx[4][2] = {}, acca[4][2] = {};
#pragma unroll
    for (int kk = 0; kk < 128; kk += 32) {
      half8 af[4];
#pragma unroll
      for (int i = 0; i < 4; i++)
        af[i] = *(const half8*)&smem[swz_h(wm + i * 16 + row, kk + quad * 8)];
#pragma unroll
      for (int jj = 0; jj < 2; jj++) {
        const size_t wo = (size_t)(wn + (jp * 2 + jj) * 16 + row) * 128 + kk + quad * 8;
        const half8 bx = *(const half8*)&WxB[wo];
        const half8 ba = *(const half8*)&WaB[wo];
#pragma unroll
        for (int i = 0; i < 4; i++) {
          accx[i][jj] = __builtin_amdgcn_mfma_f32_16x16x32_f16(af[i], bx, accx[i][jj], 0, 0, 0);
          acca[i][jj] = __builtin_amdgcn_mfma_f32_16x16x32_f16(af[i], ba, acca[i][jj], 0, 0, 0);
        }
      }
    }
    float bxv[2], bav[2], cd[2];
#pragma unroll
    for (int jj = 0; jj < 2; jj++) {
      const int d = n0 + wn + (jp * 2 + jj) * 16 + row;
      bxv[jj] = bgx[d]; bav[jj] = bga[d];
      cd[jj] = log1pf(expf(arp[d]));   // softplus inline
    }
    float Arun[2] = {1.f, 1.f}, Hrun[2] = {0.f, 0.f};
#pragma unroll
    for (int i = 0; i < 4; i++) {
      float Aseg[2] = {1.f, 1.f}, Hseg[2] = {0.f, 0.f};
#pragma unroll
      for (int r = 0; r < 4; r++) {
        const int tl = wm + i * 16 + quad * 4 + r;
        const size_t rowbase = (size_t)(m0 + tl) * DH + n0 + wn + row;
        _Float16 ah[2], gh[2];
#pragma unroll
        for (int jj = 0; jj < 2; jj++) {
          const float px = accx[i][jj][r] + bxv[jj];
          const float pa = acca[i][jj][r] + bav[jj];
          const float sx = 1.f / (1.f + __expf(-px));
          const float sa = 1.f / (1.f + __expf(-pa));
          const float a = __expf(-8.f * sa * cd[jj]);
          const float n2 = fmaxf(1.f - a * a, 0.f);
          const float xv = (float)smem[swz_h(tl, wn + (jp * 2 + jj) * 16 + row)];
          ah[jj] = (_Float16)a;
          gh[jj] = (_Float16)(sx * xv * sqrtf(n2));
          const float ar = (float)ah[jj], gr = (float)gh[jj];   // rounded, matches p3
          Aseg[jj] *= ar;
          Hseg[jj] = fmaf(ar, Hseg[jj], gr);
        }
#pragma unroll
        for (int jj = 0; jj < 2; jj++) a_out[rowbase + (jp * 2 + jj) * 16] = ah[jj];
#pragma unroll
        for (int jj = 0; jj < 2; jj++) gx_out[rowbase + (jp * 2 + jj) * 16] = gh[jj];
      }
      // cross-quad combine (token order q0..q3), fold into running
#pragma unroll
      for (int jj = 0; jj < 2; jj++) {
        float A1 = Aseg[jj], H1 = Hseg[jj];
        float A2 = __shfl_down(A1, 16, 64), H2 = __shfl_down(H1, 16, 64);
        H1 = fmaf(A2, H1, H2); A1 *= A2;
        A2 = __shfl_down(A1, 32, 64); H2 = __shfl_down(H1, 32, 64);
        H1 = fmaf(A2, H1, H2); A1 *= A2;
        Hrun[jj] = fmaf(A1, Hrun[jj], H1);
        Arun[jj] *= A1;
      }
    }
    // carry store, [c][g] layout (valid in quad 0 after the combine)
    if (lane < 16) {
#pragma unroll
      for (int jj = 0; jj < 2; jj++) {
        cA[cbase + (jp * 2 + jj) * 16] = Arun[jj];
        cH[cbase + (jp * 2 + jj) * 16] = Hrun[jj];
      }
    }
  }
}

// ---------------------------------------------------------------- scan p2/p3
// p2: one wave per channel g; lane = chunk. 6-step shfl inclusive scan with
// segment composition (A2*A1, A2*H1+H2); exclusive shift gives chunk carry-in.
__global__ __launch_bounds__(256)
void scan_p2(const float* __restrict__ cA, const float* __restrict__ cH,
             const float* __restrict__ h0, float* __restrict__ cin,
             float* __restrict__ hlast) {
  const int wave = threadIdx.x >> 6, lane = threadIdx.x & 63;
  const int g = blockIdx.x * 4 + wave;   // [0, B_SZ*DH)
  float A = cA[(size_t)lane * (B_SZ * DH) + g], H = cH[(size_t)lane * (B_SZ * DH) + g];
#pragma unroll
  for (int d = 1; d < 64; d <<= 1) {
    const float Ap = __shfl_up(A, d, 64), Hp = __shfl_up(H, d, 64);
    if (lane >= d) { H = fmaf(A, Hp, H); A *= Ap; }
  }
  const float h0g = h0[g];
  if (lane == 63) hlast[g] = fmaf(A, h0g, H);
  float Ae = __shfl_up(A, 1, 64), He = __shfl_up(H, 1, 64);
  if (lane == 0) { Ae = 1.f; He = 0.f; }
  cin[(size_t)lane * (B_SZ * DH) + g] = fmaf(Ae, h0g, He);
}

__global__ __launch_bounds__(256)
void scan_p3(const _Float16* __restrict__ a, const _Float16* __restrict__ gx,
             const float* __restrict__ cin, _Float16* __restrict__ h) {
  const int gtid = blockIdx.x * 256 + threadIdx.x;
  const int d = gtid & (DH - 1);
  const int bc = gtid >> 10;
  const int b = bc >> 6, c = bc & (NCHUNK - 1);
  const size_t base = ((size_t)(b * SEQ + c * CHUNK)) * DH + d;
  float carry = cin[c * (B_SZ * DH) + b * DH + d];   // block = 256 consecutive d -> coalesced
#pragma unroll 4
  for (int i = 0; i < CHUNK; i++) {
    const float av = (float)a[base + (size_t)i * DH];
    const float gv = (float)gx[base + (size_t)i * DH];
    carry = fmaf(av, carry, gv);
    h[base + (size_t)i * DH] = (_Float16)carry;
  }
}

// ---------------------------------------------------------------- launch
extern "C" void kernel_launch(void* const* d_in, const int* in_sizes, int n_in,
                              void* d_out, int out_size, void* d_ws, size_t ws_size,
                              hipStream_t stream) {
  const float* x     = (const float*)d_in[0];
  const float* h0    = (const float*)d_in[1];
  const float* W_in  = (const float*)d_in[2];
  const float* b_in  = (const float*)d_in[3];
  const float* Wgx   = (const float*)d_in[4];
  const float* bgx   = (const float*)d_in[5];
  const float* Wga   = (const float*)d_in[6];
  const float* bga   = (const float*)d_in[7];
  const float* arp   = (const float*)d_in[8];
  const float* W_out = (const float*)d_in[9];
  const float* b_out = (const float*)d_in[10];
  float* out = (float*)d_out;
  float* hlast = out + (size_t)MTOK * DOUT;

  char* p = (char*)d_ws;
  auto take = [&](size_t bytes) { char* r = p; p += (bytes + 255) & ~(size_t)255; return r; };
  _Float16* x_h   = (_Float16*)take((size_t)MTOK * DIN * 2);   // reused as h_buf
  _Float16* a_buf = (_Float16*)take((size_t)MTOK * DH * 2);
  _Float16* gxb   = (_Float16*)take((size_t)MTOK * DH * 2);
  _Float16* WinT  = (_Float16*)take((size_t)DIN * DH * 2);
  _Float16* WoutT = (_Float16*)take((size_t)DH * DOUT * 2);
  _Float16* WgxT  = (_Float16*)take((size_t)NBLK * 128 * 128 * 2);
  _Float16* WgaT  = (_Float16*)take((size_t)NBLK * 128 * 128 * 2);
  float* cA   = (float*)take((size_t)NCHUNK * B_SZ * DH * 4);
  float* cH   = (float*)take((size_t)NCHUNK * B_SZ * DH * 4);
  float* cin  = (float*)take((size_t)NCHUNK * B_SZ * DH * 4);
  _Float16* h_buf = x_h;   // x_h dead after gemm1_gates

  prep_kernel<<<16384 + 576, 256, 0, stream>>>(x, x_h, W_in, W_out, Wgx, Wga,
                                               WinT, WoutT, WgxT, WgaT);
  gemm1_gates<<<dim3(MTOK / 128, NBLK), 256, 0, stream>>>(
      x_h, WinT, b_in, WgxT, WgaT, bgx, bga, arp, a_buf, gxb, cA, cH);
  scan_p2<<<(B_SZ * DH) / 4, 256, 0, stream>>>(cA, cH, h0, cin, hlast);
  scan_p3<<<(B_SZ * NCHUNK * DH) / 256, 256, 0, stream>>>(a_buf, gxb, cin, h_buf);
  gemm_bt<1><<<dim3(MTOK / 128, DOUT / 128), 256, 0, stream>>>(h_buf, WoutT, b_out, out, MTOK, DOUT, DH);
}

// Round 2
// 314.682 us; speedup vs baseline: 1.1913x; 1.1913x over previous
//
#include <hip/hip_runtime.h>

#define B_SZ 4
#define SEQ 4096
#define DIN 1024
#define DH 1024
#define DOUT 1024
#define NBLK 8
#define MTOK (B_SZ * SEQ)      // 16384 tokens
#define CHUNK 64
#define NCHUNK (SEQ / CHUNK)   // 64

typedef _Float16 half8 __attribute__((ext_vector_type(8)));
typedef _Float16 half4v __attribute__((ext_vector_type(4)));
typedef float f32x4 __attribute__((ext_vector_type(4)));

union HPack { unsigned int u; _Float16 h[2]; };

// async global->LDS, 16B per lane. LDS dest must be wave-uniform; HW scatters
// to base + lane*16 (so LDS tiles are UNPADDED and laid out in lane order).
__device__ __forceinline__ void gl_lds16(const void* g, void* l) {
  __builtin_amdgcn_global_load_lds((__attribute__((address_space(1))) void*)g,
                                   (__attribute__((address_space(3))) void*)l,
                                   16, 0, 0);
}

// Swizzled xp-tile index (returns HALF index). byte = r*256 + c*2, XOR'd with
// (r&7)<<4. For the gate A-frag ds_read_b128 (16 rows x 4 16B-col-slots per
// wave) this gives a UNIFORM 8 lanes per 16B bank slot — the bandwidth minimum
// for a wave64 b128 read (1KB/instr); no layout can do better for this shape.
// 16B alignment preserved (XOR touches byte bits 4..6 only).
__device__ __forceinline__ int swz_h(int r, int c) {
  return (((r << 8) | (c << 1)) ^ ((r & 7) << 4)) >> 1;
}

// ---------------------------------------------------------------- prep
// One dispatch: blocks [0,16384) convert x fp32->fp16 (float4/thread);
// blocks [16384, 16384+576) do the 4 weight transposes (fp32->fp16, [R][C]->[C][R]).
__global__ __launch_bounds__(256)
void prep_kernel(const float* __restrict__ x, _Float16* __restrict__ x_h,
                 const float* __restrict__ Win, const float* __restrict__ Wout,
                 const float* __restrict__ Wgx, const float* __restrict__ Wga,
                 _Float16* __restrict__ WinT, _Float16* __restrict__ WoutT,
                 _Float16* __restrict__ WgxT, _Float16* __restrict__ WgaT) {
  __shared__ float tile[64][65];
  if (blockIdx.x < 16384) {
    const int gid = blockIdx.x * 256 + threadIdx.x;
    const float4 v = ((const float4*)x)[gid];
    half4v h;
    h[0] = (_Float16)v.x; h[1] = (_Float16)v.y; h[2] = (_Float16)v.z; h[3] = (_Float16)v.w;
    ((half4v*)x_h)[gid] = h;
    return;
  }
  int t = blockIdx.x - 16384;
  const float* src; _Float16* dst; int C; size_t bo = 0;
  if (t < 256)      { src = Win;  dst = WinT;  C = 1024; }
  else if (t < 512) { src = Wout; dst = WoutT; C = 1024; t -= 256; }
  else if (t < 544) { int u = t - 512; src = Wgx; dst = WgxT; C = 128;
                      bo = (size_t)(u >> 2) * (128 * 128); t = u & 3; }
  else              { int u = t - 544; src = Wga; dst = WgaT; C = 128;
                      bo = (size_t)(u >> 2) * (128 * 128); t = u & 3; }
  const int nbx = C >> 6;
  const int r0 = (t / nbx) * 64, c0 = (t % nbx) * 64;
  const int tr = threadIdx.x >> 6, tc = threadIdx.x & 63;
#pragma unroll
  for (int i = 0; i < 64; i += 4)
    tile[tr + i][tc] = src[bo + (size_t)(r0 + tr + i) * C + c0 + tc];
  __syncthreads();
#pragma unroll
  for (int i = 0; i < 64; i += 4) {
    const int cc = i + tr;
    dst[bo + (size_t)(c0 + cc) * C + r0 + tc] = (_Float16)tile[tc][cc];
  }
}

// ---------------------------------------------------------------- GEMM (m97 recipe)
// C[M,N] = A[M,K] * Bt[N,K]^T + bias ; 128x128 tile, 4 waves, BK=64, f16 MFMA.
template <int OUT_F32>
__global__ __launch_bounds__(256)
void gemm_bt(const _Float16* __restrict__ A, const _Float16* __restrict__ Bt,
             const float* __restrict__ bias, void* __restrict__ C,
             int M, int N, int K) {
  __shared__ __align__(16) _Float16 As[128 * 64];
  __shared__ __align__(16) _Float16 Bs[128 * 64];
  const int tid = threadIdx.x;
  const int wave = tid >> 6, lane = tid & 63;
  const int m0 = blockIdx.x * 128, n0 = blockIdx.y * 128;
  const int wm = (wave >> 1) * 64, wn = (wave & 1) * 64;
  const int row = lane & 15, quad = lane >> 4;
  const int srow = lane >> 3, scol = (lane & 7) * 8;

  f32x4 acc[4][4] = {};
  for (int kt = 0; kt < K; kt += 64) {
#pragma unroll
    for (int ci = 0; ci < 4; ci++) {
      const int c = wave * 4 + ci;
      gl_lds16(A  + (size_t)(m0 + c * 8 + srow) * K + kt + scol, As + c * 512);
      gl_lds16(Bt + (size_t)(n0 + c * 8 + srow) * K + kt + scol, Bs + c * 512);
    }
    __syncthreads();
#pragma unroll
    for (int kk = 0; kk < 64; kk += 32) {
      half8 af[4], bf[4];
#pragma unroll
      for (int i = 0; i < 4; i++)
        af[i] = *(const half8*)&As[(wm + i * 16 + row) * 64 + kk + quad * 8];
#pragma unroll
      for (int i = 0; i < 4; i++)
        bf[i] = *(const half8*)&Bs[(wn + i * 16 + row) * 64 + kk + quad * 8];
#pragma unroll
      for (int i = 0; i < 4; i++)
#pragma unroll
        for (int j = 0; j < 4; j++)
          acc[i][j] = __builtin_amdgcn_mfma_f32_16x16x32_f16(af[i], bf[j], acc[i][j], 0, 0, 0);
    }
    __syncthreads();
  }
  float bv[4];
#pragma unroll
  for (int j = 0; j < 4; j++) bv[j] = bias[n0 + wn + j * 16 + row];
#pragma unroll
  for (int i = 0; i < 4; i++) {
#pragma unroll
    for (int r = 0; r < 4; r++) {
      const int m = m0 + wm + i * 16 + quad * 4 + r;
      const size_t base = (size_t)m * N + n0 + wn + row;
#pragma unroll
      for (int j = 0; j < 4; j++) {
        const float v = acc[i][j][r] + bv[j];
        if (OUT_F32) ((float*)C)[base + j * 16] = v;
        else         ((_Float16*)C)[base + j * 16] = (_Float16)v;
      }
    }
  }
}

// ---------------------------------------------------------------- gemm1 + gates (fused)
// R1 post-mortem: fused kernel was latency-bound at VGPR=132 -> 3 waves/SIMD
// -> only 768 of 1024 blocks resident (1/3-occupancy tail round). R2 changes:
// (1) __launch_bounds__(256,4) forces VGPR<=128 -> 4 waves/SIMD, the WHOLE
//     grid resident (1024 blocks = 256 CU x 4), no tail, +33% latency hiding.
// (2) (a,gx) stores packed as one u32 in FRAGMENT-ORDER global layout:
//     idx = ((mblk*8+nb)*4+wave)*4096 + ((i*4+r)*4+j)*64 + lane
//     -> every wave store instr writes a contiguous 256B segment (was 64
//     scalar 2B stores in 32B segments). scan_p3 reads the same layout back.
// Gate accumulators stay SPLIT in two j-pair passes (64 VGPRs at a time); jp
// loop is NOT unrolled so only one pass's accs are live (rule #20 safe: all
// register arrays statically indexed).
__global__ __launch_bounds__(256, 4)
void gemm1_gates(const _Float16* __restrict__ A, const _Float16* __restrict__ Bt,
                 const float* __restrict__ bias,
                 const _Float16* __restrict__ WxT, const _Float16* __restrict__ WaT,
                 const float* __restrict__ bgx, const float* __restrict__ bga,
                 const float* __restrict__ arp,
                 unsigned int* __restrict__ ag,
                 float* __restrict__ cA, float* __restrict__ cH) {
  __shared__ __align__(16) _Float16 smem[128 * 128];   // 32KB: As|Bs, then xp tile
  _Float16* const As = smem;
  _Float16* const Bs = smem + 128 * 64;
  const int tid = threadIdx.x;
  const int wave = tid >> 6, lane = tid & 63;
  const int m0 = blockIdx.x * 128, nb = blockIdx.y, n0 = nb * 128;
  const int wm = (wave >> 1) * 64, wn = (wave & 1) * 64;
  const int row = lane & 15, quad = lane >> 4;
  const int srow = lane >> 3, scol = (lane & 7) * 8;

  // ---- xp = x_h @ WinT^T + b_in (m97 main loop, K = DIN)
  f32x4 acc[4][4] = {};
#pragma unroll 1
  for (int kt = 0; kt < DIN; kt += 64) {
#pragma unroll
    for (int ci = 0; ci < 4; ci++) {
      const int c = wave * 4 + ci;
      gl_lds16(A  + (size_t)(m0 + c * 8 + srow) * DIN + kt + scol, As + c * 512);
      gl_lds16(Bt + (size_t)(n0 + c * 8 + srow) * DIN + kt + scol, Bs + c * 512);
    }
    __syncthreads();
#pragma unroll
    for (int kk = 0; kk < 64; kk += 32) {
      half8 af[4], bf[4];
#pragma unroll
      for (int i = 0; i < 4; i++)
        af[i] = *(const half8*)&As[(wm + i * 16 + row) * 64 + kk + quad * 8];
#pragma unroll
      for (int i = 0; i < 4; i++)
        bf[i] = *(const half8*)&Bs[(wn + i * 16 + row) * 64 + kk + quad * 8];
#pragma unroll
      for (int i = 0; i < 4; i++)
#pragma unroll
        for (int j = 0; j < 4; j++)
          acc[i][j] = __builtin_amdgcn_mfma_f32_16x16x32_f16(af[i], bf[j], acc[i][j], 0, 0, 0);
    }
    __syncthreads();   // last iter: all waves done reading As/Bs -> safe to overwrite
  }

  // ---- xp tile -> swizzled LDS (fp16). acc is DEAD after this block.
  {
    float bv[4];
#pragma unroll
    for (int j = 0; j < 4; j++) bv[j] = bias[n0 + wn + j * 16 + row];
#pragma unroll
    for (int i = 0; i < 4; i++)
#pragma unroll
      for (int r = 0; r < 4; r++) {
        const int tl = wm + i * 16 + quad * 4 + r;
#pragma unroll
        for (int j = 0; j < 4; j++)
          smem[swz_h(tl, wn + j * 16 + row)] = (_Float16)(acc[i][j][r] + bv[j]);
      }
  }
  __syncthreads();

  // ---- gate GEMMs + gate math + per-chunk (A,H) reduction (scan p1)
  const _Float16* const WxB = WxT + (size_t)nb * (128 * 128);
  const _Float16* const WaB = WaT + (size_t)nb * (128 * 128);
  const int b_idx = (m0 + wm) >> 12;
  const int c_idx = ((m0 + wm) & (SEQ - 1)) >> 6;
  const int cbase = c_idx * (B_SZ * DH) + b_idx * DH + n0 + wn + row;
  const size_t agbase = ((size_t)(blockIdx.x * NBLK + nb) * 4 + wave) * 4096;

#pragma unroll 1   // do NOT unroll: keeps one pass's 64 acc VGPRs live at a time
  for (int jp = 0; jp < 2; jp++) {
    f32x4 accx[4][2] = {}, acca[4][2] = {};
#pragma unroll
    for (int kk = 0; kk < 128; kk += 32) {
      half8 af[4];
#pragma unroll
      for (int i = 0; i < 4; i++)
        af[i] = *(const half8*)&smem[swz_h(wm + i * 16 + row, kk + quad * 8)];
#pragma unroll
      for (int jj = 0; jj < 2; jj++) {
        const size_t wo = (size_t)(wn + (jp * 2 + jj) * 16 + row) * 128 + kk + quad * 8;
        const half8 bx = *(const half8*)&WxB[wo];
        const half8 ba = *(const half8*)&WaB[wo];
#pragma unroll
        for (int i = 0; i < 4; i++) {
          accx[i][jj] = __builtin_amdgcn_mfma_f32_16x16x32_f16(af[i], bx, accx[i][jj], 0, 0, 0);
          acca[i][jj] = __builtin_amdgcn_mfma_f32_16x16x32_f16(af[i], ba, acca[i][jj], 0, 0, 0);
        }
      }
    }
    float bxv[2], bav[2], cd[2];
#pragma unroll
    for (int jj = 0; jj < 2; jj++) {
      const int d = n0 + wn + (jp * 2 + jj) * 16 + row;
      bxv[jj] = bgx[d]; bav[jj] = bga[d];
      cd[jj] = log1pf(expf(arp[d]));   // softplus inline
    }
    float Arun[2] = {1.f, 1.f}, Hrun[2] = {0.f, 0.f};
#pragma unroll
    for (int i = 0; i < 4; i++) {
      float Aseg[2] = {1.f, 1.f}, Hseg[2] = {0.f, 0.f};
#pragma unroll
      for (int r = 0; r < 4; r++) {
        const int tl = wm + i * 16 + quad * 4 + r;
#pragma unroll
        for (int jj = 0; jj < 2; jj++) {
          const float px = accx[i][jj][r] + bxv[jj];
          const float pa = acca[i][jj][r] + bav[jj];
          const float sx = 1.f / (1.f + __expf(-px));
          const float sa = 1.f / (1.f + __expf(-pa));
          const float a = __expf(-8.f * sa * cd[jj]);
          const float n2 = fmaxf(1.f - a * a, 0.f);
          const float xv = (float)smem[swz_h(tl, wn + (jp * 2 + jj) * 16 + row)];
          HPack pk;
          pk.h[0] = (_Float16)a;
          pk.h[1] = (_Float16)(sx * xv * sqrtf(n2));
          // one u32 store per element: wave writes a contiguous 256B segment
          ag[agbase + (size_t)(((i * 4 + r) * 4) + jp * 2 + jj) * 64 + lane] = pk.u;
          const float ar = (float)pk.h[0], gr = (float)pk.h[1];   // rounded, matches p3
          Aseg[jj] *= ar;
          Hseg[jj] = fmaf(ar, Hseg[jj], gr);
        }
      }
      // cross-quad combine (token order q0..q3), fold into running
#pragma unroll
      for (int jj = 0; jj < 2; jj++) {
        float A1 = Aseg[jj], H1 = Hseg[jj];
        float A2 = __shfl_down(A1, 16, 64), H2 = __shfl_down(H1, 16, 64);
        H1 = fmaf(A2, H1, H2); A1 *= A2;
        A2 = __shfl_down(A1, 32, 64); H2 = __shfl_down(H1, 32, 64);
        H1 = fmaf(A2, H1, H2); A1 *= A2;
        Hrun[jj] = fmaf(A1, Hrun[jj], H1);
        Arun[jj] *= A1;
      }
    }
    // carry store, [c][g] layout (valid in quad 0 after the combine)
    if (lane < 16) {
#pragma unroll
      for (int jj = 0; jj < 2; jj++) {
        cA[cbase + (jp * 2 + jj) * 16] = Arun[jj];
        cH[cbase + (jp * 2 + jj) * 16] = Hrun[jj];
      }
    }
  }
}

// ---------------------------------------------------------------- scan p2/p3
// p2: one wave per channel g; lane = chunk. 6-step shfl inclusive scan with
// segment composition (A2*A1, A2*H1+H2); exclusive shift gives chunk carry-in.
__global__ __launch_bounds__(256)
void scan_p2(const float* __restrict__ cA, const float* __restrict__ cH,
             const float* __restrict__ h0, float* __restrict__ cin,
             float* __restrict__ hlast) {
  const int wave = threadIdx.x >> 6, lane = threadIdx.x & 63;
  const int g = blockIdx.x * 4 + wave;   // [0, B_SZ*DH)
  float A = cA[(size_t)lane * (B_SZ * DH) + g], H = cH[(size_t)lane * (B_SZ * DH) + g];
#pragma unroll
  for (int d = 1; d < 64; d <<= 1) {
    const float Ap = __shfl_up(A, d, 64), Hp = __shfl_up(H, d, 64);
    if (lane >= d) { H = fmaf(A, Hp, H); A *= Ap; }
  }
  const float h0g = h0[g];
  if (lane == 63) hlast[g] = fmaf(A, h0g, H);
  float Ae = __shfl_up(A, 1, 64), He = __shfl_up(H, 1, 64);
  if (lane == 0) { Ae = 1.f; He = 0.f; }
  cin[(size_t)lane * (B_SZ * DH) + g] = fmaf(Ae, h0g, He);
}

// p3 reads the packed fragment-order (a,gx) buffer written by gemm1_gates.
// Element (token m, channel d): mblk=m>>7, wmb=(m>>6)&1, i=((m&63)>>4),
// quad=(m>>2)&3, r=m&3; nb=d>>7, wnb=(d>>6)&1, j=(d>>4)&3, row=d&15;
// idx = ((mblk*8+nb)*4 + wmb*2+wnb)*4096 + ((i*4+r)*4+j)*64 + quad*16 + row.
// For fixed t, 64 consecutive d -> 4 contiguous 64B segments (coalesced).
__global__ __launch_bounds__(256)
void scan_p3(const unsigned int* __restrict__ ag,
             const float* __restrict__ cin, _Float16* __restrict__ h) {
  const int gtid = blockIdx.x * 256 + threadIdx.x;
  const int d = gtid & (DH - 1);
  const int bc = gtid >> 10;
  const int b = bc >> 6, c = bc & (NCHUNK - 1);
  const int mblk = b * 32 + (c >> 1), wmb = c & 1;
  const int nb = d >> 7, wnb = (d >> 6) & 1, j = (d >> 4) & 3, row = d & 15;
  const size_t agb = ((size_t)(mblk * NBLK + nb) * 4 + wmb * 2 + wnb) * 4096
                   + j * 64 + row;
  const size_t hbase = ((size_t)(b * SEQ + c * CHUNK)) * DH + d;
  float carry = cin[c * (B_SZ * DH) + b * DH + d];
#pragma unroll 4
  for (int t = 0; t < CHUNK; t++) {
    HPack pk;
    pk.u = ag[agb + (size_t)(((t >> 4) * 4 + (t & 3)) * 4) * 64 + ((t >> 2) & 3) * 16];
    const float av = (float)pk.h[0];
    const float gv = (float)pk.h[1];
    carry = fmaf(av, carry, gv);
    h[hbase + (size_t)t * DH] = (_Float16)carry;
  }
}

// ---------------------------------------------------------------- launch
extern "C" void kernel_launch(void* const* d_in, const int* in_sizes, int n_in,
                              void* d_out, int out_size, void* d_ws, size_t ws_size,
                              hipStream_t stream) {
  const float* x     = (const float*)d_in[0];
  const float* h0    = (const float*)d_in[1];
  const float* W_in  = (const float*)d_in[2];
  const float* b_in  = (const float*)d_in[3];
  const float* Wgx   = (const float*)d_in[4];
  const float* bgx   = (const float*)d_in[5];
  const float* Wga   = (const float*)d_in[6];
  const float* bga   = (const float*)d_in[7];
  const float* arp   = (const float*)d_in[8];
  const float* W_out = (const float*)d_in[9];
  const float* b_out = (const float*)d_in[10];
  float* out = (float*)d_out;
  float* hlast = out + (size_t)MTOK * DOUT;

  char* p = (char*)d_ws;
  auto take = [&](size_t bytes) { char* r = p; p += (bytes + 255) & ~(size_t)255; return r; };
  _Float16* x_h   = (_Float16*)take((size_t)MTOK * DIN * 2);   // reused as h_buf
  unsigned int* ag = (unsigned int*)take((size_t)MTOK * DH * 4);
  _Float16* WinT  = (_Float16*)take((size_t)DIN * DH * 2);
  _Float16* WoutT = (_Float16*)take((size_t)DH * DOUT * 2);
  _Float16* WgxT  = (_Float16*)take((size_t)NBLK * 128 * 128 * 2);
  _Float16* WgaT  = (_Float16*)take((size_t)NBLK * 128 * 128 * 2);
  float* cA   = (float*)take((size_t)NCHUNK * B_SZ * DH * 4);
  float* cH   = (float*)take((size_t)NCHUNK * B_SZ * DH * 4);
  float* cin  = (float*)take((size_t)NCHUNK * B_SZ * DH * 4);
  _Float16* h_buf = x_h;   // x_h dead after gemm1_gates

  prep_kernel<<<16384 + 576, 256, 0, stream>>>(x, x_h, W_in, W_out, Wgx, Wga,
                                               WinT, WoutT, WgxT, WgaT);
  gemm1_gates<<<dim3(MTOK / 128, NBLK), 256, 0, stream>>>(
      x_h, WinT, b_in, WgxT, WgaT, bgx, bga, arp, ag, cA, cH);
  scan_p2<<<(B_SZ * DH) / 4, 256, 0, stream>>>(cA, cH, h0, cin, hlast);
  scan_p3<<<(B_SZ * NCHUNK * DH) / 256, 256, 0, stream>>>(ag, cin, h_buf);
  gemm_bt<1><<<dim3(MTOK / 128, DOUT / 128), 256, 0, stream>>>(h_buf, WoutT, b_out, out, MTOK, DOUT, DH);
}

// Round 3
// 300.103 us; speedup vs baseline: 1.2492x; 1.0486x over previous
//
#include <hip/hip_runtime.h>

#define B_SZ 4
#define SEQ 4096
#define DIN 1024
#define DH 1024
#define DOUT 1024
#define NBLK 8
#define MTOK (B_SZ * SEQ)      // 16384 tokens
#define CHUNK 64
#define NCHUNK (SEQ / CHUNK)   // 64

typedef _Float16 half8 __attribute__((ext_vector_type(8)));
typedef _Float16 half4v __attribute__((ext_vector_type(4)));
typedef float f32x4 __attribute__((ext_vector_type(4)));

union HPack { unsigned int u; _Float16 h[2]; };

// async global->LDS, 16B per lane. LDS dest must be wave-uniform; HW scatters
// to base + lane*16 (so LDS tiles are UNPADDED and laid out in lane order).
__device__ __forceinline__ void gl_lds16(const void* g, void* l) {
  __builtin_amdgcn_global_load_lds((__attribute__((address_space(1))) void*)g,
                                   (__attribute__((address_space(3))) void*)l,
                                   16, 0, 0);
}

// Swizzled xp-tile index (returns HALF index). byte = r*256 + c*2, XOR'd with
// (r&7)<<4. For the gate A-frag ds_read_b128 (16 rows x 4 16B-col-slots per
// wave) this gives a UNIFORM 8 lanes per 16B bank slot — the bandwidth minimum
// for a wave64 b128 read (1KB/instr). 16B alignment preserved.
__device__ __forceinline__ int swz_h(int r, int c) {
  return (((r << 8) | (c << 1)) ^ ((r & 7) << 4)) >> 1;
}

// ---------------------------------------------------------------- prep
// One dispatch: blocks [0,16384) convert x fp32->fp16 (float4/thread);
// blocks [16384, 16384+576) do the 4 weight transposes (fp32->fp16, [R][C]->[C][R]).
__global__ __launch_bounds__(256)
void prep_kernel(const float* __restrict__ x, _Float16* __restrict__ x_h,
                 const float* __restrict__ Win, const float* __restrict__ Wout,
                 const float* __restrict__ Wgx, const float* __restrict__ Wga,
                 _Float16* __restrict__ WinT, _Float16* __restrict__ WoutT,
                 _Float16* __restrict__ WgxT, _Float16* __restrict__ WgaT) {
  __shared__ float tile[64][65];
  if (blockIdx.x < 16384) {
    const int gid = blockIdx.x * 256 + threadIdx.x;
    const float4 v = ((const float4*)x)[gid];
    half4v h;
    h[0] = (_Float16)v.x; h[1] = (_Float16)v.y; h[2] = (_Float16)v.z; h[3] = (_Float16)v.w;
    ((half4v*)x_h)[gid] = h;
    return;
  }
  int t = blockIdx.x - 16384;
  const float* src; _Float16* dst; int C; size_t bo = 0;
  if (t < 256)      { src = Win;  dst = WinT;  C = 1024; }
  else if (t < 512) { src = Wout; dst = WoutT; C = 1024; t -= 256; }
  else if (t < 544) { int u = t - 512; src = Wgx; dst = WgxT; C = 128;
                      bo = (size_t)(u >> 2) * (128 * 128); t = u & 3; }
  else              { int u = t - 544; src = Wga; dst = WgaT; C = 128;
                      bo = (size_t)(u >> 2) * (128 * 128); t = u & 3; }
  const int nbx = C >> 6;
  const int r0 = (t / nbx) * 64, c0 = (t % nbx) * 64;
  const int tr = threadIdx.x >> 6, tc = threadIdx.x & 63;
#pragma unroll
  for (int i = 0; i < 64; i += 4)
    tile[tr + i][tc] = src[bo + (size_t)(r0 + tr + i) * C + c0 + tc];
  __syncthreads();
#pragma unroll
  for (int i = 0; i < 64; i += 4) {
    const int cc = i + tr;
    dst[bo + (size_t)(c0 + cc) * C + r0 + tc] = (_Float16)tile[tc][cc];
  }
}

// ---------------------------------------------------------------- GEMM (m97 recipe)
// C[M,N] = A[M,K] * Bt[N,K]^T + bias ; 128x128 tile, 4 waves, BK=64, f16 MFMA.
// R3: __launch_bounds__(256,4) — same lever that took the fused kernel
// 166->104 us: forces acc into AGPRs (VGPR<=128), whole 1024-block grid
// resident (4 blocks/CU), no 1/3-occupancy tail round.
template <int OUT_F32>
__global__ __launch_bounds__(256, 4)
void gemm_bt(const _Float16* __restrict__ A, const _Float16* __restrict__ Bt,
             const float* __restrict__ bias, void* __restrict__ C,
             int M, int N, int K) {
  __shared__ __align__(16) _Float16 As[128 * 64];
  __shared__ __align__(16) _Float16 Bs[128 * 64];
  const int tid = threadIdx.x;
  const int wave = tid >> 6, lane = tid & 63;
  const int m0 = blockIdx.x * 128, n0 = blockIdx.y * 128;
  const int wm = (wave >> 1) * 64, wn = (wave & 1) * 64;
  const int row = lane & 15, quad = lane >> 4;
  const int srow = lane >> 3, scol = (lane & 7) * 8;

  f32x4 acc[4][4] = {};
#pragma unroll 1
  for (int kt = 0; kt < K; kt += 64) {
#pragma unroll
    for (int ci = 0; ci < 4; ci++) {
      const int c = wave * 4 + ci;
      gl_lds16(A  + (size_t)(m0 + c * 8 + srow) * K + kt + scol, As + c * 512);
      gl_lds16(Bt + (size_t)(n0 + c * 8 + srow) * K + kt + scol, Bs + c * 512);
    }
    __syncthreads();
#pragma unroll
    for (int kk = 0; kk < 64; kk += 32) {
      half8 af[4], bf[4];
#pragma unroll
      for (int i = 0; i < 4; i++)
        af[i] = *(const half8*)&As[(wm + i * 16 + row) * 64 + kk + quad * 8];
#pragma unroll
      for (int i = 0; i < 4; i++)
        bf[i] = *(const half8*)&Bs[(wn + i * 16 + row) * 64 + kk + quad * 8];
#pragma unroll
      for (int i = 0; i < 4; i++)
#pragma unroll
        for (int j = 0; j < 4; j++)
          acc[i][j] = __builtin_amdgcn_mfma_f32_16x16x32_f16(af[i], bf[j], acc[i][j], 0, 0, 0);
    }
    __syncthreads();
  }
  float bv[4];
#pragma unroll
  for (int j = 0; j < 4; j++) bv[j] = bias[n0 + wn + j * 16 + row];
#pragma unroll
  for (int i = 0; i < 4; i++) {
#pragma unroll
    for (int r = 0; r < 4; r++) {
      const int m = m0 + wm + i * 16 + quad * 4 + r;
      const size_t base = (size_t)m * N + n0 + wn + row;
#pragma unroll
      for (int j = 0; j < 4; j++) {
        const float v = acc[i][j][r] + bv[j];
        if (OUT_F32) ((float*)C)[base + j * 16] = v;
        else         ((_Float16*)C)[base + j * 16] = (_Float16)v;
      }
    }
  }
}

// ---------------------------------------------------------------- gemm1 + gates (fused)
// (unchanged from R2 — 104 us steady-state; VGPR=64+AGPR, occ 37%)
__global__ __launch_bounds__(256, 4)
void gemm1_gates(const _Float16* __restrict__ A, const _Float16* __restrict__ Bt,
                 const float* __restrict__ bias,
                 const _Float16* __restrict__ WxT, const _Float16* __restrict__ WaT,
                 const float* __restrict__ bgx, const float* __restrict__ bga,
                 const float* __restrict__ arp,
                 unsigned int* __restrict__ ag,
                 float* __restrict__ cA, float* __restrict__ cH) {
  __shared__ __align__(16) _Float16 smem[128 * 128];   // 32KB: As|Bs, then xp tile
  _Float16* const As = smem;
  _Float16* const Bs = smem + 128 * 64;
  const int tid = threadIdx.x;
  const int wave = tid >> 6, lane = tid & 63;
  const int m0 = blockIdx.x * 128, nb = blockIdx.y, n0 = nb * 128;
  const int wm = (wave >> 1) * 64, wn = (wave & 1) * 64;
  const int row = lane & 15, quad = lane >> 4;
  const int srow = lane >> 3, scol = (lane & 7) * 8;

  // ---- xp = x_h @ WinT^T + b_in (m97 main loop, K = DIN)
  f32x4 acc[4][4] = {};
#pragma unroll 1
  for (int kt = 0; kt < DIN; kt += 64) {
#pragma unroll
    for (int ci = 0; ci < 4; ci++) {
      const int c = wave * 4 + ci;
      gl_lds16(A  + (size_t)(m0 + c * 8 + srow) * DIN + kt + scol, As + c * 512);
      gl_lds16(Bt + (size_t)(n0 + c * 8 + srow) * DIN + kt + scol, Bs + c * 512);
    }
    __syncthreads();
#pragma unroll
    for (int kk = 0; kk < 64; kk += 32) {
      half8 af[4], bf[4];
#pragma unroll
      for (int i = 0; i < 4; i++)
        af[i] = *(const half8*)&As[(wm + i * 16 + row) * 64 + kk + quad * 8];
#pragma unroll
      for (int i = 0; i < 4; i++)
        bf[i] = *(const half8*)&Bs[(wn + i * 16 + row) * 64 + kk + quad * 8];
#pragma unroll
      for (int i = 0; i < 4; i++)
#pragma unroll
        for (int j = 0; j < 4; j++)
          acc[i][j] = __builtin_amdgcn_mfma_f32_16x16x32_f16(af[i], bf[j], acc[i][j], 0, 0, 0);
    }
    __syncthreads();   // last iter: all waves done reading As/Bs -> safe to overwrite
  }

  // ---- xp tile -> swizzled LDS (fp16). acc is DEAD after this block.
  {
    float bv[4];
#pragma unroll
    for (int j = 0; j < 4; j++) bv[j] = bias[n0 + wn + j * 16 + row];
#pragma unroll
    for (int i = 0; i < 4; i++)
#pragma unroll
      for (int r = 0; r < 4; r++) {
        const int tl = wm + i * 16 + quad * 4 + r;
#pragma unroll
        for (int j = 0; j < 4; j++)
          smem[swz_h(tl, wn + j * 16 + row)] = (_Float16)(acc[i][j][r] + bv[j]);
      }
  }
  __syncthreads();

  // ---- gate GEMMs + gate math + per-chunk (A,H) reduction (scan p1)
  const _Float16* const WxB = WxT + (size_t)nb * (128 * 128);
  const _Float16* const WaB = WaT + (size_t)nb * (128 * 128);
  const int b_idx = (m0 + wm) >> 12;
  const int c_idx = ((m0 + wm) & (SEQ - 1)) >> 6;
  const int cbase = c_idx * (B_SZ * DH) + b_idx * DH + n0 + wn + row;
  const size_t agbase = ((size_t)(blockIdx.x * NBLK + nb) * 4 + wave) * 4096;

#pragma unroll 1   // do NOT unroll: keeps one pass's 64 acc VGPRs live at a time
  for (int jp = 0; jp < 2; jp++) {
    f32x4 accx[4][2] = {}, acca[4][2] = {};
#pragma unroll
    for (int kk = 0; kk < 128; kk += 32) {
      half8 af[4];
#pragma unroll
      for (int i = 0; i < 4; i++)
        af[i] = *(const half8*)&smem[swz_h(wm + i * 16 + row, kk + quad * 8)];
#pragma unroll
      for (int jj = 0; jj < 2; jj++) {
        const size_t wo = (size_t)(wn + (jp * 2 + jj) * 16 + row) * 128 + kk + quad * 8;
        const half8 bx = *(const half8*)&WxB[wo];
        const half8 ba = *(const half8*)&WaB[wo];
#pragma unroll
        for (int i = 0; i < 4; i++) {
          accx[i][jj] = __builtin_amdgcn_mfma_f32_16x16x32_f16(af[i], bx, accx[i][jj], 0, 0, 0);
          acca[i][jj] = __builtin_amdgcn_mfma_f32_16x16x32_f16(af[i], ba, acca[i][jj], 0, 0, 0);
        }
      }
    }
    float bxv[2], bav[2], cd[2];
#pragma unroll
    for (int jj = 0; jj < 2; jj++) {
      const int d = n0 + wn + (jp * 2 + jj) * 16 + row;
      bxv[jj] = bgx[d]; bav[jj] = bga[d];
      cd[jj] = log1pf(expf(arp[d]));   // softplus inline
    }
    float Arun[2] = {1.f, 1.f}, Hrun[2] = {0.f, 0.f};
#pragma unroll
    for (int i = 0; i < 4; i++) {
      float Aseg[2] = {1.f, 1.f}, Hseg[2] = {0.f, 0.f};
#pragma unroll
      for (int r = 0; r < 4; r++) {
        const int tl = wm + i * 16 + quad * 4 + r;
#pragma unroll
        for (int jj = 0; jj < 2; jj++) {
          const float px = accx[i][jj][r] + bxv[jj];
          const float pa = acca[i][jj][r] + bav[jj];
          const float sx = 1.f / (1.f + __expf(-px));
          const float sa = 1.f / (1.f + __expf(-pa));
          const float a = __expf(-8.f * sa * cd[jj]);
          const float n2 = fmaxf(1.f - a * a, 0.f);
          const float xv = (float)smem[swz_h(tl, wn + (jp * 2 + jj) * 16 + row)];
          HPack pk;
          pk.h[0] = (_Float16)a;
          pk.h[1] = (_Float16)(sx * xv * sqrtf(n2));
          // one u32 store per element: wave writes a contiguous 256B segment
          ag[agbase + (size_t)(((i * 4 + r) * 4) + jp * 2 + jj) * 64 + lane] = pk.u;
          const float ar = (float)pk.h[0], gr = (float)pk.h[1];   // rounded, matches p3
          Aseg[jj] *= ar;
          Hseg[jj] = fmaf(ar, Hseg[jj], gr);
        }
      }
      // cross-quad combine (token order q0..q3), fold into running
#pragma unroll
      for (int jj = 0; jj < 2; jj++) {
        float A1 = Aseg[jj], H1 = Hseg[jj];
        float A2 = __shfl_down(A1, 16, 64), H2 = __shfl_down(H1, 16, 64);
        H1 = fmaf(A2, H1, H2); A1 *= A2;
        A2 = __shfl_down(A1, 32, 64); H2 = __shfl_down(H1, 32, 64);
        H1 = fmaf(A2, H1, H2); A1 *= A2;
        Hrun[jj] = fmaf(A1, Hrun[jj], H1);
        Arun[jj] *= A1;
      }
    }
    // carry store, [c][g] layout (valid in quad 0 after the combine)
    if (lane < 16) {
#pragma unroll
      for (int jj = 0; jj < 2; jj++) {
        cA[cbase + (jp * 2 + jj) * 16] = Arun[jj];
        cH[cbase + (jp * 2 + jj) * 16] = Hrun[jj];
      }
    }
  }
}

// ---------------------------------------------------------------- scan p2/p3
// p2: one wave per channel g; lane = chunk. 6-step shfl inclusive scan with
// segment composition (A2*A1, A2*H1+H2); exclusive shift gives chunk carry-in.
__global__ __launch_bounds__(256)
void scan_p2(const float* __restrict__ cA, const float* __restrict__ cH,
             const float* __restrict__ h0, float* __restrict__ cin,
             float* __restrict__ hlast) {
  const int wave = threadIdx.x >> 6, lane = threadIdx.x & 63;
  const int g = blockIdx.x * 4 + wave;   // [0, B_SZ*DH)
  float A = cA[(size_t)lane * (B_SZ * DH) + g], H = cH[(size_t)lane * (B_SZ * DH) + g];
#pragma unroll
  for (int d = 1; d < 64; d <<= 1) {
    const float Ap = __shfl_up(A, d, 64), Hp = __shfl_up(H, d, 64);
    if (lane >= d) { H = fmaf(A, Hp, H); A *= Ap; }
  }
  const float h0g = h0[g];
  if (lane == 63) hlast[g] = fmaf(A, h0g, H);
  float Ae = __shfl_up(A, 1, 64), He = __shfl_up(H, 1, 64);
  if (lane == 0) { Ae = 1.f; He = 0.f; }
  cin[(size_t)lane * (B_SZ * DH) + g] = fmaf(Ae, h0g, He);
}

// p3 reads the packed fragment-order (a,gx) buffer written by gemm1_gates.
// R3: unroll 8 — loads are carry-independent; deeper unroll keeps more VMEM
// in flight in this latency-bound loop (only the fma chain is serial).
__global__ __launch_bounds__(256)
void scan_p3(const unsigned int* __restrict__ ag,
             const float* __restrict__ cin, _Float16* __restrict__ h) {
  const int gtid = blockIdx.x * 256 + threadIdx.x;
  const int d = gtid & (DH - 1);
  const int bc = gtid >> 10;
  const int b = bc >> 6, c = bc & (NCHUNK - 1);
  const int mblk = b * 32 + (c >> 1), wmb = c & 1;
  const int nb = d >> 7, wnb = (d >> 6) & 1, j = (d >> 4) & 3, row = d & 15;
  const size_t agb = ((size_t)(mblk * NBLK + nb) * 4 + wmb * 2 + wnb) * 4096
                   + j * 64 + row;
  const size_t hbase = ((size_t)(b * SEQ + c * CHUNK)) * DH + d;
  float carry = cin[c * (B_SZ * DH) + b * DH + d];
#pragma unroll 8
  for (int t = 0; t < CHUNK; t++) {
    HPack pk;
    pk.u = ag[agb + (size_t)(((t >> 4) * 4 + (t & 3)) * 4) * 64 + ((t >> 2) & 3) * 16];
    const float av = (float)pk.h[0];
    const float gv = (float)pk.h[1];
    carry = fmaf(av, carry, gv);
    h[hbase + (size_t)t * DH] = (_Float16)carry;
  }
}

// ---------------------------------------------------------------- launch
extern "C" void kernel_launch(void* const* d_in, const int* in_sizes, int n_in,
                              void* d_out, int out_size, void* d_ws, size_t ws_size,
                              hipStream_t stream) {
  const float* x     = (const float*)d_in[0];
  const float* h0    = (const float*)d_in[1];
  const float* W_in  = (const float*)d_in[2];
  const float* b_in  = (const float*)d_in[3];
  const float* Wgx   = (const float*)d_in[4];
  const float* bgx   = (const float*)d_in[5];
  const float* Wga   = (const float*)d_in[6];
  const float* bga   = (const float*)d_in[7];
  const float* arp   = (const float*)d_in[8];
  const float* W_out = (const float*)d_in[9];
  const float* b_out = (const float*)d_in[10];
  float* out = (float*)d_out;
  float* hlast = out + (size_t)MTOK * DOUT;

  char* p = (char*)d_ws;
  auto take = [&](size_t bytes) { char* r = p; p += (bytes + 255) & ~(size_t)255; return r; };
  _Float16* x_h   = (_Float16*)take((size_t)MTOK * DIN * 2);   // reused as h_buf
  unsigned int* ag = (unsigned int*)take((size_t)MTOK * DH * 4);
  _Float16* WinT  = (_Float16*)take((size_t)DIN * DH * 2);
  _Float16* WoutT = (_Float16*)take((size_t)DH * DOUT * 2);
  _Float16* WgxT  = (_Float16*)take((size_t)NBLK * 128 * 128 * 2);
  _Float16* WgaT  = (_Float16*)take((size_t)NBLK * 128 * 128 * 2);
  float* cA   = (float*)take((size_t)NCHUNK * B_SZ * DH * 4);
  float* cH   = (float*)take((size_t)NCHUNK * B_SZ * DH * 4);
  float* cin  = (float*)take((size_t)NCHUNK * B_SZ * DH * 4);
  _Float16* h_buf = x_h;   // x_h dead after gemm1_gates

  prep_kernel<<<16384 + 576, 256, 0, stream>>>(x, x_h, W_in, W_out, Wgx, Wga,
                                               WinT, WoutT, WgxT, WgaT);
  gemm1_gates<<<dim3(MTOK / 128, NBLK), 256, 0, stream>>>(
      x_h, WinT, b_in, WgxT, WgaT, bgx, bga, arp, ag, cA, cH);
  scan_p2<<<(B_SZ * DH) / 4, 256, 0, stream>>>(cA, cH, h0, cin, hlast);
  scan_p3<<<(B_SZ * NCHUNK * DH) / 256, 256, 0, stream>>>(ag, cin, h_buf);
  gemm_bt<1><<<dim3(MTOK / 128, DOUT / 128), 256, 0, stream>>>(h_buf, WoutT, b_out, out, MTOK, DOUT, DH);
}